// Round 7
// baseline (304.196 us; speedup 1.0000x reference)
//
#include <hip/hip_runtime.h>

#define DIM 128

typedef float fx4 __attribute__((ext_vector_type(4)));

// ---------------------------------------------------------------------------
// Kernel 1: per-graph start offsets from sorted segment_ids.
// offs[g] = first row with seg >= g ; offs[G] = N. Handles empty graphs.
// ---------------------------------------------------------------------------
__global__ void k_offsets(const int* __restrict__ seg, int* __restrict__ offs,
                          int n, int ngraphs) {
    const int i = blockIdx.x * blockDim.x + threadIdx.x;
    const int a = (i < n) ? seg[i] : 0;
    int p = __shfl_up(a, 1);          // all lanes participate before any exit
    if (i >= n) return;
    if (i == 0) {
        for (int g = 0; g <= a; ++g) offs[g] = 0;
    } else {
        if ((threadIdx.x & 63) == 0) p = seg[i - 1];   // wave boundary
        for (int g = p + 1; g <= a; ++g) offs[g] = i;
    }
    if (i == n - 1) {
        for (int g = a + 1; g <= ngraphs; ++g) offs[g] = n;
    }
}

// ---------------------------------------------------------------------------
// Kernel 2: segment sums for graphs [g0, g0+gcount). 8 blocks per graph,
// 256 threads: tx = float4 column, ty = row slot. Dual accumulators.
// Deterministic per-eighth partials (no atomics). partial: [8][G][DIM].
// The chunk's ~128 MB of h streams through L3 and stays resident for the
// chunk's scatter that immediately follows.
// ---------------------------------------------------------------------------
__global__ __launch_bounds__(256) void k_segsum(const float* __restrict__ h,
                                                const int* __restrict__ offs,
                                                float* __restrict__ partial,
                                                int ngraphs, int g0) {
    const int b = blockIdx.x;
    const int g = g0 + (b >> 3);
    const int q = b & 7;
    const int s = offs[g];
    const int e = offs[g + 1];
    const int n = e - s;
    const int per = (n + 7) >> 3;
    const int rs = s + q * per;
    const int re = min(rs + per, e);

    const int tx = threadIdx.x & 31;   // float4 column
    const int ty = threadIdx.x >> 5;   // row slot (8 rows in flight)

    fx4 acc  = {0.f, 0.f, 0.f, 0.f};
    fx4 acc2 = {0.f, 0.f, 0.f, 0.f};
    int r = rs + ty;
    for (; r + 8 < re; r += 16) {
        acc  += *reinterpret_cast<const fx4*>(h + (size_t)r * DIM + tx * 4);
        acc2 += *reinterpret_cast<const fx4*>(h + (size_t)(r + 8) * DIM + tx * 4);
    }
    if (r < re)
        acc += *reinterpret_cast<const fx4*>(h + (size_t)r * DIM + tx * 4);
    acc += acc2;

    __shared__ fx4 red[8][32];
    red[ty][tx] = acc;
    __syncthreads();
    if (ty == 0) {
        fx4 t = red[0][tx];
        #pragma unroll
        for (int i = 1; i < 8; ++i) t += red[i][tx];
        *reinterpret_cast<fx4*>(
            partial + ((size_t)q * ngraphs + g) * DIM + tx * 4) = t;
    }
}

// ---------------------------------------------------------------------------
// Kernel 3: virtual-node update for graphs [g0, g0+gcount). One block per
// graph, 128 threads. pool = sum/count ; vn_new = vn_h + relu((vn_h+pool)@W+b)
// ---------------------------------------------------------------------------
__global__ __launch_bounds__(128) void k_vn(const float* __restrict__ vn_h,
                                            const float* __restrict__ W,
                                            const float* __restrict__ bias,
                                            const float* __restrict__ partial,
                                            const int* __restrict__ offs,
                                            float* __restrict__ vn_out,
                                            int ngraphs, int g0) {
    const int g = g0 + blockIdx.x;
    const int d = threadIdx.x;
    const int cnt = offs[g + 1] - offs[g];
    const float inv = 1.0f / (float)max(cnt, 1);

    float sum = 0.f;
    #pragma unroll
    for (int p = 0; p < 8; ++p)
        sum += partial[((size_t)p * ngraphs + g) * DIM + d];
    const float vh = vn_h[(size_t)g * DIM + d];
    const float x = vh + sum * inv;

    __shared__ float xs[DIM];
    xs[d] = x;
    __syncthreads();

    float dot = bias[d];
    #pragma unroll
    for (int k = 0; k < DIM; ++k)
        dot = fmaf(xs[k], W[k * DIM + d], dot);

    vn_out[(size_t)g * DIM + d] = vh + fmaxf(dot, 0.0f);
}

// ---------------------------------------------------------------------------
// Kernel 4: h_new = h + vn_new[seg] for the chunk's rows. The chunk's h was
// just streamed by k_segsum and is L3-resident -> reads are L3 hits; h_out
// uses nontemporal stores so the write stream doesn't evict the chunk.
// scan_mode (last chunk only): never touch offs/partial (they live in a
// stash inside this chunk's h_out rows when d_ws is too small) — instead
// grid-stride ALL rows and process those with seg[r] >= g0.
// ---------------------------------------------------------------------------
__global__ __launch_bounds__(256) void k_scatter(const float* __restrict__ h,
                                                 const int* __restrict__ seg,
                                                 const float* __restrict__ vn_new,
                                                 float* __restrict__ h_out,
                                                 const int* __restrict__ offs,
                                                 int g0, int g1, int n,
                                                 int scan_mode) {
    const int stride = gridDim.x * blockDim.x;
    if (!scan_mode) {
        const int i0 = offs[g0] * (DIM / 4);
        const int i1 = offs[g1] * (DIM / 4);
        for (int i = i0 + blockIdx.x * blockDim.x + threadIdx.x; i < i1; i += stride) {
            const int r = i >> 5;
            const int c = (i & 31) * 4;
            const int g = seg[r];
            const fx4 hv = *reinterpret_cast<const fx4*>(h + (size_t)r * DIM + c);
            const fx4 vv = *reinterpret_cast<const fx4*>(vn_new + (size_t)g * DIM + c);
            const fx4 o = hv + vv;
            __builtin_nontemporal_store(
                o, reinterpret_cast<fx4*>(h_out + (size_t)r * DIM + c));
        }
    } else {
        const int total = n * (DIM / 4);
        for (int i = blockIdx.x * blockDim.x + threadIdx.x; i < total; i += stride) {
            const int r = i >> 5;
            const int g = seg[r];
            if (g < g0) continue;              // not in this (last) chunk
            const int c = (i & 31) * 4;
            const fx4 hv = *reinterpret_cast<const fx4*>(h + (size_t)r * DIM + c);
            const fx4 vv = *reinterpret_cast<const fx4*>(vn_new + (size_t)g * DIM + c);
            const fx4 o = hv + vv;
            __builtin_nontemporal_store(
                o, reinterpret_cast<fx4*>(h_out + (size_t)r * DIM + c));
        }
    }
}

// ---------------------------------------------------------------------------
extern "C" void kernel_launch(void* const* d_in, const int* in_sizes, int n_in,
                              void* d_out, int out_size, void* d_ws, size_t ws_size,
                              hipStream_t stream) {
    const float* h    = (const float*)d_in[0];
    const float* vn_h = (const float*)d_in[1];
    const int*   seg  = (const int*)d_in[2];
    const float* W    = (const float*)d_in[3];
    const float* bias = (const float*)d_in[4];

    const int N = in_sizes[0] / DIM;   // 1,000,000
    const int G = in_sizes[1] / DIM;   // 1024

    float* out    = (float*)d_out;
    float* vn_out = out;                       // [G*DIM]
    float* h_out  = out + (size_t)G * DIM;     // [N*DIM]

    // Scratch: partial sums [8][G][DIM] f32 + offs [G+1] int.
    const size_t partial_floats = (size_t)8 * G * DIM;
    size_t stash_floats = partial_floats + (size_t)(G + 1);
    stash_floats = (stash_floats + 3) & ~(size_t)3;          // 16B-align base
    const size_t need = stash_floats * sizeof(float);

    float* partial;
    int*   offs;
    if (ws_size >= need) {
        partial = (float*)d_ws;
        offs    = (int*)((char*)d_ws + partial_floats * sizeof(float));
    } else {
        // Stash at the TAIL of h_out: only the LAST chunk's scatter writes
        // these rows, and that scatter runs in scan_mode (reads only seg),
        // after every read of partial/offs has completed. The stash rows
        // are then rewritten with correct h_new values before validation.
        float* base = h_out + (size_t)N * DIM - stash_floats;
        partial = base;
        offs    = (int*)(base + partial_floats);
    }

    hipLaunchKernelGGL(k_offsets, dim3((N + 255) / 256), dim3(256), 0, stream,
                       seg, offs, N, G);

    // 4 chunks of G/4 graphs (~128 MB of h each — fits Infinity Cache).
    const int NCHUNK = 4;
    const int gpc = G / NCHUNK;                // 256
    for (int c = 0; c < NCHUNK; ++c) {
        const int g0 = c * gpc;
        const int g1 = (c == NCHUNK - 1) ? G : g0 + gpc;
        const int gc = g1 - g0;
        const int scan_mode = (c == NCHUNK - 1) ? 1 : 0;

        hipLaunchKernelGGL(k_segsum, dim3(gc * 8), dim3(256), 0, stream,
                           h, offs, partial, G, g0);
        hipLaunchKernelGGL(k_vn, dim3(gc), dim3(DIM), 0, stream,
                           vn_h, W, bias, partial, offs, vn_out, G, g0);
        hipLaunchKernelGGL(k_scatter, dim3(2048), dim3(256), 0, stream,
                           h, seg, vn_out, h_out, offs, g0, g1, N, scan_mode);
    }
}